// Round 4
// baseline (8894.165 us; speedup 1.0000x reference)
//
#include <hip/hip_runtime.h>

typedef unsigned int u32;
typedef unsigned short u16;
typedef float f32x4 __attribute__((ext_vector_type(4)));
typedef short bf16x8 __attribute__((ext_vector_type(8)));
typedef u16 u16x4 __attribute__((ext_vector_type(4)));

#define N_NODES 100000
#define N_EDGES 3200000
#define MPAD 100096   // 782 * 128

__device__ __forceinline__ float bf2f(u16 b) { return __uint_as_float(((u32)b) << 16); }
__device__ __forceinline__ u16 f2bf(float f) {
  u32 u = __float_as_uint(f);
  u += 0x7fffu + ((u >> 16) & 1u);   // RNE
  return (u16)(u >> 16);
}

// ---------------- setup kernels ----------------

__global__ void count_kernel(const int* __restrict__ src, const int* __restrict__ dst,
                             int* deg, int* indeg) {
  int i = blockIdx.x * blockDim.x + threadIdx.x;
  if (i < N_EDGES) {
    atomicAdd(&deg[src[i]], 1);
    atomicAdd(&indeg[dst[i]], 1);
  }
}

__global__ void dis_kernel(const int* __restrict__ deg, float* __restrict__ dis) {
  int v = blockIdx.x * blockDim.x + threadIdx.x;
  if (v < N_NODES) dis[v] = deg[v] > 0 ? 1.0f / sqrtf((float)deg[v]) : 0.f;
}

// single-block exclusive scan, n = N_NODES
__global__ void scan_kernel(const int* __restrict__ in, int* __restrict__ rp,
                            int* __restrict__ cur, int n) {
  __shared__ int wtot[16];
  __shared__ int woff[16];
  const int tid = threadIdx.x;
  const int lane = tid & 63, wid = tid >> 6;
  int carry = 0;
  for (int base = 0; base < n; base += 1024) {
    int i = base + tid;
    int v = (i < n) ? in[i] : 0;
    int s = v;
#pragma unroll
    for (int off = 1; off < 64; off <<= 1) {
      int t = __shfl_up(s, off, 64);
      if (lane >= off) s += t;
    }
    if (lane == 63) wtot[wid] = s;
    __syncthreads();
    if (wid == 0) {
      int t = (lane < 16) ? wtot[lane] : 0;
#pragma unroll
      for (int off = 1; off < 16; off <<= 1) {
        int u = __shfl_up(t, off, 64);
        if (lane >= off) t += u;
      }
      if (lane < 16) woff[lane] = t;
    }
    __syncthreads();
    int wexcl = (wid == 0) ? 0 : woff[wid - 1];
    int excl = carry + wexcl + (s - v);
    if (i < n) { rp[i] = excl; cur[i] = excl; }
    carry += woff[15];
    __syncthreads();
  }
  if (tid == 0) rp[n] = carry;
}

__global__ void scatter_kernel(const int* __restrict__ src, const int* __restrict__ dst,
                               const float* __restrict__ dis, int* cursor,
                               int* __restrict__ ssrc, float* __restrict__ sw) {
  int i = blockIdx.x * blockDim.x + threadIdx.x;
  if (i >= N_EDGES) return;
  int s = src[i], d = dst[i];
  int pos = atomicAdd(&cursor[d], 1);
  ssrc[pos] = s;
  sw[pos] = -dis[s] * dis[d];
}

// W (3 x fi x fo fp32) -> plane-major hi/lo bf16: WTh[t*NP*PW + n*PW + r]
__global__ void wt_kernel(const float* __restrict__ W, u16* __restrict__ WTh,
                          u16* __restrict__ WTl, int fi, int fo, int PW, int NP) {
  int idx = blockIdx.x * blockDim.x + threadIdx.x;
  if (idx >= 3 * fi * fo) return;
  int k = idx / fo, n = idx - k * fo;
  int t = k / fi, r = k - t * fi;
  float w = W[idx];
  u16 hb = f2bf(w);
  u16 lb = f2bf(w - bf2f(hb));
  size_t dst_i = (size_t)t * NP * PW + (size_t)n * PW + r;
  WTh[dst_i] = hb;
  WTl[dst_i] = lb;
}

// fp32 plane [MPAD][PW] -> bf16 hi plane GH [MPAD][PW] + lo plane at GH + MPAD*PW.
// Zeroes pad rows (>= N_NODES) and pad cols (>= fi).
__global__ __launch_bounds__(256) void cast_kernel(const float* __restrict__ P,
                                                   u16* __restrict__ GH, int PWSH, int fi) {
  const int PW = 1 << PWSH;
  int i4 = blockIdx.x * 256 + threadIdx.x;
  int row = i4 >> (PWSH - 2);
  if (row >= MPAD) return;
  int c = (i4 & ((PW >> 2) - 1)) << 2;
  float4 v = make_float4(0.f, 0.f, 0.f, 0.f);
  if (row < N_NODES) v = *reinterpret_cast<const float4*>(P + (size_t)row * PW + c);
  float f[4] = {v.x, v.y, v.z, v.w};
  u16x4 h, l;
#pragma unroll
  for (int q = 0; q < 4; ++q) {
    float val = (c + q < fi) ? f[q] : 0.f;
    u16 hb = f2bf(val);
    h[q] = hb;
    l[q] = f2bf(val - bf2f(hb));
  }
  u16* GL = GH + (size_t)MPAD * PW;
  *reinterpret_cast<u16x4*>(GH + (size_t)row * PW + c) = h;
  *reinterpret_cast<u16x4*>(GL + (size_t)row * PW + c) = l;
}

// ---------------- propagation (fp32): out[v] = dosub ? 2*acc - t0[v] : acc
template <int NC2, int F2>
__global__ __launch_bounds__(256) void prop_kernel(
    const int* __restrict__ rp, const int* __restrict__ ssrc, const float* __restrict__ sw,
    const float* __restrict__ in, const float* __restrict__ t0p, float* __restrict__ outp,
    int PW, int dosub) {
  int v = blockIdx.x * 4 + (threadIdx.x >> 6);
  if (v >= N_NODES) return;
  int lane = threadIdx.x & 63;
  float ax[NC2], ay[NC2];
#pragma unroll
  for (int c = 0; c < NC2; ++c) { ax[c] = 0.f; ay[c] = 0.f; }
  int e1 = rp[v + 1];
  for (int j = rp[v]; j < e1; ++j) {
    int s = ssrc[j];
    float wv = sw[j];
    const float2* row = reinterpret_cast<const float2*>(in + (size_t)s * PW);
#pragma unroll
    for (int c = 0; c < NC2; ++c) {
      int idx = c * 64 + lane;
      if (NC2 * 64 == F2 || idx < F2) {
        float2 p = row[idx];
        ax[c] += wv * p.x;
        ay[c] += wv * p.y;
      }
    }
  }
  float2* orow = reinterpret_cast<float2*>(outp + (size_t)v * PW);
  const float2* srow = reinterpret_cast<const float2*>(t0p + (size_t)v * PW);
#pragma unroll
  for (int c = 0; c < NC2; ++c) {
    int idx = c * 64 + lane;
    if (NC2 * 64 == F2 || idx < F2) {
      float xv = ax[c], yv = ay[c];
      if (dosub) {
        float2 q = srow[idx];
        xv = 2.f * xv - q.x;
        yv = 2.f * yv - q.y;
      }
      orow[idx] = make_float2(xv, yv);
    }
  }
}

// ---------------- GEMM: C = relu(A @ B^T + b), pre-cast bf16 hi/lo operands.
// Block 128x128, 4 waves (2x2 of 64x64), BK=64, ONE barrier pair + 96 MFMA per k-tile.
// A planes: pair base per Chebyshev plane (hi [MPAD][PW], lo at +MPAD*PW).
// B planes: plane-major (BH + p*NP*PW).
// Staging: per-lane uint4 global load -> XOR-swizzled ds_write_b128 (R1-verified
// involution: LDS[row][chunk^(row&7)], read applies same XOR -> zero bank conflicts).
// Loads issued before the barrier so they overlap the previous k-tile's MFMA tail.
__global__ __launch_bounds__(256, 2) void gemm_kernel(
    const u16* __restrict__ A0, const u16* __restrict__ A1, const u16* __restrict__ A2,
    const u16* __restrict__ BH, const u16* __restrict__ BL,
    int PWSH, int NP, const float* __restrict__ bias, float* __restrict__ C,
    int ostride, int fo, int mlimit) {
  __shared__ u16 lds[4 * 128 * 64];   // Ah | Al | Bh | Bl, 16 KiB each
  const int tid = threadIdx.x;
  const int lane = tid & 63;
  const int wave = tid >> 6;
  const int m0 = blockIdx.x * 128;
  const int n0 = blockIdx.y * 128;

  // staging geometry: thread handles (row = tid>>3 [+ i*32], 16B chunk = tid&7)
  const int srow = tid >> 3;                       // 0..31
  const int schk = tid & 7;
  const int swo = (schk ^ (srow & 7)) * 8;         // swizzled u16 col offset in LDS row
  const size_t aoff = (((size_t)(m0 + srow)) << (PWSH + 1)) + schk * 16;
  const size_t boff = (((size_t)(n0 + srow)) << (PWSH + 1)) + schk * 16;
  const int rowadv = 32 << (PWSH + 1);             // 32 rows, in bytes

  const size_t planeA = (size_t)MPAD << PWSH;      // u16 elems (lo-plane offset)
  const size_t planeB = (size_t)NP << PWSH;

  const int wm = (wave & 1) * 64;
  const int wn = (wave >> 1) * 64;
  const int lsw = (lane & 7) << 3;
  const int tpp = 1 << (PWSH - 6);                 // k-tiles per plane

  f32x4 acc[4][4] = {};

  for (int p = 0; p < 3; ++p) {
    const u16* Ab = (p == 0) ? A0 : (p == 1 ? A1 : A2);
    const char* ga_h = (const char*)Ab + aoff;
    const char* ga_l = (const char*)(Ab + planeA) + aoff;
    const char* gb_h = (const char*)(BH + p * planeB) + boff;
    const char* gb_l = (const char*)(BL + p * planeB) + boff;
    for (int t = 0; t < tpp; ++t) {
      uint4 vah[4], val[4], vbh[4], vbl[4];
#pragma unroll
      for (int i = 0; i < 4; ++i) {
        const size_t ro = (size_t)i * rowadv;
        vah[i] = *reinterpret_cast<const uint4*>(ga_h + ro);
        val[i] = *reinterpret_cast<const uint4*>(ga_l + ro);
        vbh[i] = *reinterpret_cast<const uint4*>(gb_h + ro);
        vbl[i] = *reinterpret_cast<const uint4*>(gb_l + ro);
      }
      ga_h += 128; ga_l += 128; gb_h += 128; gb_l += 128;
      __syncthreads();   // previous k-tile's reads done before overwrite
#pragma unroll
      for (int i = 0; i < 4; ++i) {
        const int li = (srow + i * 32) * 64 + swo;
        *reinterpret_cast<uint4*>(&lds[li]) = vah[i];
        *reinterpret_cast<uint4*>(&lds[128 * 64 + li]) = val[i];
        *reinterpret_cast<uint4*>(&lds[2 * 128 * 64 + li]) = vbh[i];
        *reinterpret_cast<uint4*>(&lds[3 * 128 * 64 + li]) = vbl[i];
      }
      __syncthreads();
#pragma unroll
      for (int ks = 0; ks < 64; ks += 32) {
        bf16x8 ah[4], al[4], bh[4], bl[4];
        const int sko = (ks + (lane >> 4) * 8) ^ lsw;
#pragma unroll
        for (int i = 0; i < 4; ++i) {
          int ra = (wm + i * 16 + (lane & 15)) * 64 + sko;
          ah[i] = *reinterpret_cast<const bf16x8*>(&lds[ra]);
          al[i] = *reinterpret_cast<const bf16x8*>(&lds[128 * 64 + ra]);
        }
#pragma unroll
        for (int j = 0; j < 4; ++j) {
          int rb = (wn + j * 16 + (lane & 15)) * 64 + sko;
          bh[j] = *reinterpret_cast<const bf16x8*>(&lds[2 * 128 * 64 + rb]);
          bl[j] = *reinterpret_cast<const bf16x8*>(&lds[3 * 128 * 64 + rb]);
        }
#pragma unroll
        for (int i = 0; i < 4; ++i)
#pragma unroll
          for (int j = 0; j < 4; ++j) {
            acc[i][j] = __builtin_amdgcn_mfma_f32_16x16x32_bf16(ah[i], bh[j], acc[i][j], 0, 0, 0);
            acc[i][j] = __builtin_amdgcn_mfma_f32_16x16x32_bf16(al[i], bh[j], acc[i][j], 0, 0, 0);
            acc[i][j] = __builtin_amdgcn_mfma_f32_16x16x32_bf16(ah[i], bl[j], acc[i][j], 0, 0, 0);
          }
      }
    }
  }

  const int qr = lane >> 4, lc = lane & 15;
#pragma unroll
  for (int jj = 0; jj < 4; ++jj) {
    int col = n0 + wn + jj * 16 + lc;
    if (col >= fo) continue;
    float bv = bias[col];
#pragma unroll
    for (int i = 0; i < 4; ++i) {
      int rowb = m0 + wm + i * 16 + qr * 4;
#pragma unroll
      for (int r = 0; r < 4; ++r) {
        int row = rowb + r;
        if (row < mlimit) {
          float vv = acc[i][jj][r] + bv;
          vv = vv > 0.f ? vv : 0.f;
          C[(size_t)row * ostride + col] = vv;
        }
      }
    }
  }
}

// ---------------- launch ----------------
extern "C" void kernel_launch(void* const* d_in, const int* in_sizes, int n_in,
                              void* d_out, int out_size, void* d_ws, size_t ws_size,
                              hipStream_t stream) {
  const float* x = (const float*)d_in[0];
  const int* ei = (const int*)d_in[1];
  const int* src = ei;
  const int* dst = ei + N_EDGES;
  const float* W1 = (const float*)d_in[2];
  const float* b1 = (const float*)d_in[3];
  const float* W2 = (const float*)d_in[4];
  const float* b2 = (const float*)d_in[5];
  const float* W3 = (const float*)d_in[6];
  const float* b3 = (const float*)d_in[7];
  float* out = (float*)d_out;

  char* ws = (char*)d_ws;
  size_t o = 0;
  auto alloc = [&](size_t bytes) { size_t r = o; o += (bytes + 255) & ~(size_t)255; return r; };
  int* deg = (int*)(ws + alloc((size_t)N_NODES * 4));
  int* indeg = (int*)(ws + alloc((size_t)N_NODES * 4));
  int* rp = (int*)(ws + alloc((size_t)(N_NODES + 1) * 4));
  int* cur = (int*)(ws + alloc((size_t)N_NODES * 4));
  float* dis = (float*)(ws + alloc((size_t)N_NODES * 4));
  int* ssrc = (int*)(ws + alloc((size_t)N_EDGES * 4));
  float* sw = (float*)(ws + alloc((size_t)N_EDGES * 4));
  u16* WT1h = (u16*)(ws + alloc((size_t)256 * 384 * 2));
  u16* WT1l = (u16*)(ws + alloc((size_t)256 * 384 * 2));
  u16* WT2h = (u16*)(ws + alloc((size_t)512 * 768 * 2));
  u16* WT2l = (u16*)(ws + alloc((size_t)512 * 768 * 2));
  u16* WT3h = (u16*)(ws + alloc((size_t)1024 * 1536 * 2));
  u16* WT3l = (u16*)(ws + alloc((size_t)1024 * 1536 * 2));

  // three 205-MB regions, lifetime-aliased; d_out doubles as P31 scratch
  const size_t PL1 = (size_t)MPAD * 128 * 4;   // fp32 plane L1 = bf16 hi+lo pair L1
  const size_t PL2 = (size_t)MPAD * 256 * 4;
  const size_t PL3 = (size_t)MPAD * 512 * 4;
  char* R0 = ws + alloc(PL3);
  char* R1 = ws + alloc(PL3);
  char* R2 = ws + alloc(PL3);

  // layer 1 planes (fp32): P10 = x (read-only), P11/P12 in R2
  float* P11 = (float*)(R2 + PL1);
  float* P12 = (float*)(R2 + 2 * PL1);
  u16* G1_0 = (u16*)R1;                    // cast pairs (hi plane + lo plane) per Cheb plane
  u16* G1_1 = (u16*)(R1 + PL1);
  u16* G1_2 = (u16*)(R1 + 2 * PL1);
  // layer 2
  float* P20 = (float*)R0;
  float* P21 = (float*)(R0 + PL2);
  float* P22 = (float*)R2;                 // over dead L1 planes
  u16* G2_0 = (u16*)R1;                    // over dead G1
  u16* G2_1 = (u16*)(R1 + PL2);
  u16* G2_2 = (u16*)(R2 + PL2);            // upper half of R2 (P22 in lower half)
  // layer 3
  float* P30 = (float*)R0;                 // over dead P20/P21 (gemm2 output)
  float* P31 = (float*)out;                // d_out as scratch (dies before gemm3 writes C)
  float* P32 = (float*)R2;                 // over dead P22/G2_2
  u16* G3_2 = (u16*)R1;                    // cast order: P32 first (frees R2) ...
  u16* G3_0 = (u16*)R2;                    // ... then P30 (frees R0) ...
  u16* G3_1 = (u16*)R0;                    // ... then P31

  hipMemsetAsync(deg, 0, (size_t)N_NODES * 4, stream);
  hipMemsetAsync(indeg, 0, (size_t)N_NODES * 4, stream);
  hipMemsetAsync(WT1h, 0, (size_t)256 * 384 * 2 * 2, stream);   // h+l contiguous
  hipMemsetAsync(WT2h, 0, (size_t)512 * 768 * 2 * 2, stream);
  hipMemsetAsync(WT3h, 0, (size_t)1024 * 1536 * 2 * 2, stream);

  count_kernel<<<(N_EDGES + 255) / 256, 256, 0, stream>>>(src, dst, deg, indeg);
  dis_kernel<<<(N_NODES + 255) / 256, 256, 0, stream>>>(deg, dis);
  scan_kernel<<<1, 1024, 0, stream>>>(indeg, rp, cur, N_NODES);
  scatter_kernel<<<(N_EDGES + 255) / 256, 256, 0, stream>>>(src, dst, dis, cur, ssrc, sw);
  wt_kernel<<<(3 * 128 * 250 + 255) / 256, 256, 0, stream>>>(W1, WT1h, WT1l, 128, 250, 128, 256);
  wt_kernel<<<(3 * 250 * 500 + 255) / 256, 256, 0, stream>>>(W2, WT2h, WT2l, 250, 500, 256, 512);
  wt_kernel<<<(3 * 500 * 1000 + 255) / 256, 256, 0, stream>>>(W3, WT3h, WT3l, 500, 1000, 512, 1024);

  dim3 pgrid((N_NODES + 3) / 4);
  const int CB1 = MPAD * 128 / 1024, CB2 = MPAD * 256 / 1024, CB3 = MPAD * 512 / 1024;

  // ---- layer 1 (fi=128, PW=128, fo=250, NP=256) ----
  prop_kernel<1, 64><<<pgrid, 256, 0, stream>>>(rp, ssrc, sw, x, x, P11, 128, 0);
  prop_kernel<1, 64><<<pgrid, 256, 0, stream>>>(rp, ssrc, sw, P11, x, P12, 128, 1);
  cast_kernel<<<CB1, 256, 0, stream>>>(x, G1_0, 7, 128);
  cast_kernel<<<CB1, 256, 0, stream>>>(P11, G1_1, 7, 128);
  cast_kernel<<<CB1, 256, 0, stream>>>(P12, G1_2, 7, 128);
  gemm_kernel<<<dim3(MPAD / 128, 2), 256, 0, stream>>>(G1_0, G1_1, G1_2, WT1h, WT1l,
                                                       7, 256, b1, P20, 256, 250, MPAD);
  // ---- layer 2 (fi=250, PW=256, fo=500, NP=512) ----
  prop_kernel<2, 125><<<pgrid, 256, 0, stream>>>(rp, ssrc, sw, P20, P20, P21, 256, 0);
  prop_kernel<2, 125><<<pgrid, 256, 0, stream>>>(rp, ssrc, sw, P21, P20, P22, 256, 1);
  cast_kernel<<<CB2, 256, 0, stream>>>(P20, G2_0, 8, 250);
  cast_kernel<<<CB2, 256, 0, stream>>>(P21, G2_1, 8, 250);
  cast_kernel<<<CB2, 256, 0, stream>>>(P22, G2_2, 8, 250);
  gemm_kernel<<<dim3(MPAD / 128, 4), 256, 0, stream>>>(G2_0, G2_1, G2_2, WT2h, WT2l,
                                                       8, 512, b2, P30, 512, 500, MPAD);
  // ---- layer 3 (fi=500, PW=512, fo=1000, NP=1024) ----
  prop_kernel<4, 250><<<pgrid, 256, 0, stream>>>(rp, ssrc, sw, P30, P30, P31, 512, 0);
  prop_kernel<4, 250><<<pgrid, 256, 0, stream>>>(rp, ssrc, sw, P31, P30, P32, 512, 1);
  cast_kernel<<<CB3, 256, 0, stream>>>(P32, G3_2, 9, 500);   // frees R2
  cast_kernel<<<CB3, 256, 0, stream>>>(P30, G3_0, 9, 500);   // frees R0
  cast_kernel<<<CB3, 256, 0, stream>>>(P31, G3_1, 9, 500);   // frees d_out
  gemm_kernel<<<dim3(MPAD / 128, 8), 256, 0, stream>>>(G3_0, G3_1, G3_2, WT3h, WT3l,
                                                       9, 1024, b3, out, 1000, 1000, N_NODES);

  (void)in_sizes; (void)n_in; (void)out_size; (void)ws_size;
}

// Round 5
// 6183.419 us; speedup vs baseline: 1.4384x; 1.4384x over previous
//
#include <hip/hip_runtime.h>

typedef unsigned int u32;
typedef unsigned short u16;
typedef float f32x4 __attribute__((ext_vector_type(4)));
typedef short bf16x8 __attribute__((ext_vector_type(8)));
typedef u16 u16x4 __attribute__((ext_vector_type(4)));

#define N_NODES 100000
#define N_EDGES 3200000
#define MPAD 100096   // 782 * 128

__device__ __forceinline__ float bf2f(u16 b) { return __uint_as_float(((u32)b) << 16); }
__device__ __forceinline__ u16 f2bf(float f) {
  u32 u = __float_as_uint(f);
  u += 0x7fffu + ((u >> 16) & 1u);   // RNE
  return (u16)(u >> 16);
}

// ---------------- setup kernels ----------------

__global__ void count_kernel(const int* __restrict__ src, const int* __restrict__ dst,
                             int* deg, int* indeg) {
  int i = blockIdx.x * blockDim.x + threadIdx.x;
  if (i < N_EDGES) {
    atomicAdd(&deg[src[i]], 1);
    atomicAdd(&indeg[dst[i]], 1);
  }
}

__global__ void dis_kernel(const int* __restrict__ deg, float* __restrict__ dis) {
  int v = blockIdx.x * blockDim.x + threadIdx.x;
  if (v < N_NODES) dis[v] = deg[v] > 0 ? 1.0f / sqrtf((float)deg[v]) : 0.f;
}

// single-block exclusive scan, n = N_NODES
__global__ void scan_kernel(const int* __restrict__ in, int* __restrict__ rp,
                            int* __restrict__ cur, int n) {
  __shared__ int wtot[16];
  __shared__ int woff[16];
  const int tid = threadIdx.x;
  const int lane = tid & 63, wid = tid >> 6;
  int carry = 0;
  for (int base = 0; base < n; base += 1024) {
    int i = base + tid;
    int v = (i < n) ? in[i] : 0;
    int s = v;
#pragma unroll
    for (int off = 1; off < 64; off <<= 1) {
      int t = __shfl_up(s, off, 64);
      if (lane >= off) s += t;
    }
    if (lane == 63) wtot[wid] = s;
    __syncthreads();
    if (wid == 0) {
      int t = (lane < 16) ? wtot[lane] : 0;
#pragma unroll
      for (int off = 1; off < 16; off <<= 1) {
        int u = __shfl_up(t, off, 64);
        if (lane >= off) t += u;
      }
      if (lane < 16) woff[lane] = t;
    }
    __syncthreads();
    int wexcl = (wid == 0) ? 0 : woff[wid - 1];
    int excl = carry + wexcl + (s - v);
    if (i < n) { rp[i] = excl; cur[i] = excl; }
    carry += woff[15];
    __syncthreads();
  }
  if (tid == 0) rp[n] = carry;
}

__global__ void scatter_kernel(const int* __restrict__ src, const int* __restrict__ dst,
                               const float* __restrict__ dis, int* cursor,
                               int* __restrict__ ssrc, float* __restrict__ sw) {
  int i = blockIdx.x * blockDim.x + threadIdx.x;
  if (i >= N_EDGES) return;
  int s = src[i], d = dst[i];
  int pos = atomicAdd(&cursor[d], 1);
  ssrc[pos] = s;
  sw[pos] = -dis[s] * dis[d];
}

// W (3 x fi x fo fp32) -> plane-major hi/lo bf16: WTh[t*NP*PW + n*PW + r]
__global__ void wt_kernel(const float* __restrict__ W, u16* __restrict__ WTh,
                          u16* __restrict__ WTl, int fi, int fo, int PW, int NP) {
  int idx = blockIdx.x * blockDim.x + threadIdx.x;
  if (idx >= 3 * fi * fo) return;
  int k = idx / fo, n = idx - k * fo;
  int t = k / fi, r = k - t * fi;
  float w = W[idx];
  u16 hb = f2bf(w);
  u16 lb = f2bf(w - bf2f(hb));
  size_t dst_i = (size_t)t * NP * PW + (size_t)n * PW + r;
  WTh[dst_i] = hb;
  WTl[dst_i] = lb;
}

// fp32 plane [MPAD][PW] -> bf16 hi plane GH [MPAD][PW] + lo plane at GH + MPAD*PW.
// Zeroes pad rows (>= N_NODES) and pad cols (>= fi).
__global__ __launch_bounds__(256) void cast_kernel(const float* __restrict__ P,
                                                   u16* __restrict__ GH, int PWSH, int fi) {
  const int PW = 1 << PWSH;
  int i4 = blockIdx.x * 256 + threadIdx.x;
  int row = i4 >> (PWSH - 2);
  if (row >= MPAD) return;
  int c = (i4 & ((PW >> 2) - 1)) << 2;
  float4 v = make_float4(0.f, 0.f, 0.f, 0.f);
  if (row < N_NODES) v = *reinterpret_cast<const float4*>(P + (size_t)row * PW + c);
  float f[4] = {v.x, v.y, v.z, v.w};
  u16x4 h, l;
#pragma unroll
  for (int q = 0; q < 4; ++q) {
    float val = (c + q < fi) ? f[q] : 0.f;
    u16 hb = f2bf(val);
    h[q] = hb;
    l[q] = f2bf(val - bf2f(hb));
  }
  u16* GL = GH + (size_t)MPAD * PW;
  *reinterpret_cast<u16x4*>(GH + (size_t)row * PW + c) = h;
  *reinterpret_cast<u16x4*>(GL + (size_t)row * PW + c) = l;
}

// ---------------- propagation (fp32): out[v] = dosub ? 2*acc - t0[v] : acc
template <int NC2, int F2>
__global__ __launch_bounds__(256) void prop_kernel(
    const int* __restrict__ rp, const int* __restrict__ ssrc, const float* __restrict__ sw,
    const float* __restrict__ in, const float* __restrict__ t0p, float* __restrict__ outp,
    int PW, int dosub) {
  int v = blockIdx.x * 4 + (threadIdx.x >> 6);
  if (v >= N_NODES) return;
  int lane = threadIdx.x & 63;
  float ax[NC2], ay[NC2];
#pragma unroll
  for (int c = 0; c < NC2; ++c) { ax[c] = 0.f; ay[c] = 0.f; }
  int e1 = rp[v + 1];
  for (int j = rp[v]; j < e1; ++j) {
    int s = ssrc[j];
    float wv = sw[j];
    const float2* row = reinterpret_cast<const float2*>(in + (size_t)s * PW);
#pragma unroll
    for (int c = 0; c < NC2; ++c) {
      int idx = c * 64 + lane;
      if (NC2 * 64 == F2 || idx < F2) {
        float2 p = row[idx];
        ax[c] += wv * p.x;
        ay[c] += wv * p.y;
      }
    }
  }
  float2* orow = reinterpret_cast<float2*>(outp + (size_t)v * PW);
  const float2* srow = reinterpret_cast<const float2*>(t0p + (size_t)v * PW);
#pragma unroll
  for (int c = 0; c < NC2; ++c) {
    int idx = c * 64 + lane;
    if (NC2 * 64 == F2 || idx < F2) {
      float xv = ax[c], yv = ay[c];
      if (dosub) {
        float2 q = srow[idx];
        xv = 2.f * xv - q.x;
        yv = 2.f * yv - q.y;
      }
      orow[idx] = make_float2(xv, yv);
    }
  }
}

// ---------------- GEMM: C = relu(A @ B^T + b), pre-cast bf16 hi/lo operands.
// Block 128x128, 4 waves (2x2 of 64x64), BK=64, ONE barrier pair + 96 MFMA per k-tile.
// Grid: dim3(nN, MPAD/128), n0 = blockIdx.x (FASTEST) -> the nN blocks sharing one
// A panel are temporally adjacent; A (615 MB @ L3-overflow) fetched from HBM once.
// Staging: two phases (A-pair then B-pair), max 8 live uint4 (32 VGPRs) to avoid the
// scratch spill measured in R4 (WRITE_SIZE 7.38 GB); sched_barrier(0) pins the phase
// split so the compiler can't re-hoist phase-B loads. XOR-swizzle involution as R1
// (LDS[row][chunk^(row&7)], read applies same XOR -> zero bank conflicts, verified).
__global__ __launch_bounds__(256, 2) void gemm_kernel(
    const u16* __restrict__ A0, const u16* __restrict__ A1, const u16* __restrict__ A2,
    const u16* __restrict__ BH, const u16* __restrict__ BL,
    int PWSH, int NP, const float* __restrict__ bias, float* __restrict__ C,
    int ostride, int fo, int mlimit) {
  __shared__ u16 lds[4 * 128 * 64];   // Ah | Al | Bh | Bl, 16 KiB each
  const int tid = threadIdx.x;
  const int lane = tid & 63;
  const int wave = tid >> 6;
  const int m0 = blockIdx.y * 128;    // n fastest, m on y
  const int n0 = blockIdx.x * 128;

  // staging geometry: thread handles (row = tid>>3 [+ i*32], 16B chunk = tid&7)
  const int srow = tid >> 3;                       // 0..31
  const int schk = tid & 7;
  const int swo = (schk ^ (srow & 7)) * 8;         // swizzled u16 col offset in LDS row
  const size_t aoff = (((size_t)(m0 + srow)) << (PWSH + 1)) + schk * 16;
  const size_t boff = (((size_t)(n0 + srow)) << (PWSH + 1)) + schk * 16;
  const int rowadv = 32 << (PWSH + 1);             // 32 rows, in bytes

  const size_t planeA = (size_t)MPAD << PWSH;      // u16 elems (lo-plane offset)
  const size_t planeB = (size_t)NP << PWSH;

  const int wm = (wave & 1) * 64;
  const int wn = (wave >> 1) * 64;
  const int lsw = (lane & 7) << 3;
  const int tpp = 1 << (PWSH - 6);                 // k-tiles per plane

  f32x4 acc[4][4] = {};

  for (int p = 0; p < 3; ++p) {
    const u16* Ab = (p == 0) ? A0 : (p == 1 ? A1 : A2);
    const char* ga_h = (const char*)Ab + aoff;
    const char* ga_l = (const char*)(Ab + planeA) + aoff;
    const char* gb_h = (const char*)(BH + p * planeB) + boff;
    const char* gb_l = (const char*)(BL + p * planeB) + boff;
    for (int t = 0; t < tpp; ++t) {
      __syncthreads();   // previous k-tile's reads done before overwrite
      // phase A: load + write A hi/lo (8 uint4 live)
      {
        uint4 th[4], tl[4];
#pragma unroll
        for (int i = 0; i < 4; ++i) {
          const size_t ro = (size_t)i * rowadv;
          th[i] = *reinterpret_cast<const uint4*>(ga_h + ro);
          tl[i] = *reinterpret_cast<const uint4*>(ga_l + ro);
        }
#pragma unroll
        for (int i = 0; i < 4; ++i) {
          const int li = (srow + i * 32) * 64 + swo;
          *reinterpret_cast<uint4*>(&lds[li]) = th[i];
          *reinterpret_cast<uint4*>(&lds[128 * 64 + li]) = tl[i];
        }
      }
      __builtin_amdgcn_sched_barrier(0);   // keep phase B loads from hoisting above
      // phase B: load + write B hi/lo (8 uint4 live)
      {
        uint4 th[4], tl[4];
#pragma unroll
        for (int i = 0; i < 4; ++i) {
          const size_t ro = (size_t)i * rowadv;
          th[i] = *reinterpret_cast<const uint4*>(gb_h + ro);
          tl[i] = *reinterpret_cast<const uint4*>(gb_l + ro);
        }
#pragma unroll
        for (int i = 0; i < 4; ++i) {
          const int li = (srow + i * 32) * 64 + swo;
          *reinterpret_cast<uint4*>(&lds[2 * 128 * 64 + li]) = th[i];
          *reinterpret_cast<uint4*>(&lds[3 * 128 * 64 + li]) = tl[i];
        }
      }
      ga_h += 128; ga_l += 128; gb_h += 128; gb_l += 128;
      __syncthreads();
#pragma unroll
      for (int ks = 0; ks < 64; ks += 32) {
        bf16x8 ah[4], al[4], bh[4], bl[4];
        const int sko = (ks + (lane >> 4) * 8) ^ lsw;
#pragma unroll
        for (int i = 0; i < 4; ++i) {
          int ra = (wm + i * 16 + (lane & 15)) * 64 + sko;
          ah[i] = *reinterpret_cast<const bf16x8*>(&lds[ra]);
          al[i] = *reinterpret_cast<const bf16x8*>(&lds[128 * 64 + ra]);
        }
#pragma unroll
        for (int j = 0; j < 4; ++j) {
          int rb = (wn + j * 16 + (lane & 15)) * 64 + sko;
          bh[j] = *reinterpret_cast<const bf16x8*>(&lds[2 * 128 * 64 + rb]);
          bl[j] = *reinterpret_cast<const bf16x8*>(&lds[3 * 128 * 64 + rb]);
        }
#pragma unroll
        for (int i = 0; i < 4; ++i)
#pragma unroll
          for (int j = 0; j < 4; ++j) {
            acc[i][j] = __builtin_amdgcn_mfma_f32_16x16x32_bf16(ah[i], bh[j], acc[i][j], 0, 0, 0);
            acc[i][j] = __builtin_amdgcn_mfma_f32_16x16x32_bf16(al[i], bh[j], acc[i][j], 0, 0, 0);
            acc[i][j] = __builtin_amdgcn_mfma_f32_16x16x32_bf16(ah[i], bl[j], acc[i][j], 0, 0, 0);
          }
      }
    }
  }

  const int qr = lane >> 4, lc = lane & 15;
#pragma unroll
  for (int jj = 0; jj < 4; ++jj) {
    int col = n0 + wn + jj * 16 + lc;
    if (col >= fo) continue;
    float bv = bias[col];
#pragma unroll
    for (int i = 0; i < 4; ++i) {
      int rowb = m0 + wm + i * 16 + qr * 4;
#pragma unroll
      for (int r = 0; r < 4; ++r) {
        int row = rowb + r;
        if (row < mlimit) {
          float vv = acc[i][jj][r] + bv;
          vv = vv > 0.f ? vv : 0.f;
          C[(size_t)row * ostride + col] = vv;
        }
      }
    }
  }
}

// ---------------- launch ----------------
extern "C" void kernel_launch(void* const* d_in, const int* in_sizes, int n_in,
                              void* d_out, int out_size, void* d_ws, size_t ws_size,
                              hipStream_t stream) {
  const float* x = (const float*)d_in[0];
  const int* ei = (const int*)d_in[1];
  const int* src = ei;
  const int* dst = ei + N_EDGES;
  const float* W1 = (const float*)d_in[2];
  const float* b1 = (const float*)d_in[3];
  const float* W2 = (const float*)d_in[4];
  const float* b2 = (const float*)d_in[5];
  const float* W3 = (const float*)d_in[6];
  const float* b3 = (const float*)d_in[7];
  float* out = (float*)d_out;

  char* ws = (char*)d_ws;
  size_t o = 0;
  auto alloc = [&](size_t bytes) { size_t r = o; o += (bytes + 255) & ~(size_t)255; return r; };
  int* deg = (int*)(ws + alloc((size_t)N_NODES * 4));
  int* indeg = (int*)(ws + alloc((size_t)N_NODES * 4));
  int* rp = (int*)(ws + alloc((size_t)(N_NODES + 1) * 4));
  int* cur = (int*)(ws + alloc((size_t)N_NODES * 4));
  float* dis = (float*)(ws + alloc((size_t)N_NODES * 4));
  int* ssrc = (int*)(ws + alloc((size_t)N_EDGES * 4));
  float* sw = (float*)(ws + alloc((size_t)N_EDGES * 4));
  u16* WT1h = (u16*)(ws + alloc((size_t)256 * 384 * 2));
  u16* WT1l = (u16*)(ws + alloc((size_t)256 * 384 * 2));
  u16* WT2h = (u16*)(ws + alloc((size_t)512 * 768 * 2));
  u16* WT2l = (u16*)(ws + alloc((size_t)512 * 768 * 2));
  u16* WT3h = (u16*)(ws + alloc((size_t)1024 * 1536 * 2));
  u16* WT3l = (u16*)(ws + alloc((size_t)1024 * 1536 * 2));

  // three 205-MB regions, lifetime-aliased; d_out doubles as P31 scratch
  const size_t PL1 = (size_t)MPAD * 128 * 4;   // fp32 plane L1 = bf16 hi+lo pair L1
  const size_t PL2 = (size_t)MPAD * 256 * 4;
  const size_t PL3 = (size_t)MPAD * 512 * 4;
  char* R0 = ws + alloc(PL3);
  char* R1 = ws + alloc(PL3);
  char* R2 = ws + alloc(PL3);

  // layer 1 planes (fp32): P10 = x (read-only), P11/P12 in R2
  float* P11 = (float*)(R2 + PL1);
  float* P12 = (float*)(R2 + 2 * PL1);
  u16* G1_0 = (u16*)R1;                    // cast pairs (hi plane + lo plane) per Cheb plane
  u16* G1_1 = (u16*)(R1 + PL1);
  u16* G1_2 = (u16*)(R1 + 2 * PL1);
  // layer 2
  float* P20 = (float*)R0;
  float* P21 = (float*)(R0 + PL2);
  float* P22 = (float*)R2;                 // over dead L1 planes
  u16* G2_0 = (u16*)R1;                    // over dead G1
  u16* G2_1 = (u16*)(R1 + PL2);
  u16* G2_2 = (u16*)(R2 + PL2);            // upper half of R2 (P22 in lower half)
  // layer 3
  float* P30 = (float*)R0;                 // over dead P20/P21 (gemm2 output)
  float* P31 = (float*)out;                // d_out as scratch (dies before gemm3 writes C)
  float* P32 = (float*)R2;                 // over dead P22/G2_2
  u16* G3_2 = (u16*)R1;                    // cast order: P32 first (frees R2) ...
  u16* G3_0 = (u16*)R2;                    // ... then P30 (frees R0) ...
  u16* G3_1 = (u16*)R0;                    // ... then P31

  hipMemsetAsync(deg, 0, (size_t)N_NODES * 4, stream);
  hipMemsetAsync(indeg, 0, (size_t)N_NODES * 4, stream);
  hipMemsetAsync(WT1h, 0, (size_t)256 * 384 * 2 * 2, stream);   // h+l contiguous
  hipMemsetAsync(WT2h, 0, (size_t)512 * 768 * 2 * 2, stream);
  hipMemsetAsync(WT3h, 0, (size_t)1024 * 1536 * 2 * 2, stream);

  count_kernel<<<(N_EDGES + 255) / 256, 256, 0, stream>>>(src, dst, deg, indeg);
  dis_kernel<<<(N_NODES + 255) / 256, 256, 0, stream>>>(deg, dis);
  scan_kernel<<<1, 1024, 0, stream>>>(indeg, rp, cur, N_NODES);
  scatter_kernel<<<(N_EDGES + 255) / 256, 256, 0, stream>>>(src, dst, dis, cur, ssrc, sw);
  wt_kernel<<<(3 * 128 * 250 + 255) / 256, 256, 0, stream>>>(W1, WT1h, WT1l, 128, 250, 128, 256);
  wt_kernel<<<(3 * 250 * 500 + 255) / 256, 256, 0, stream>>>(W2, WT2h, WT2l, 250, 500, 256, 512);
  wt_kernel<<<(3 * 500 * 1000 + 255) / 256, 256, 0, stream>>>(W3, WT3h, WT3l, 500, 1000, 512, 1024);

  dim3 pgrid((N_NODES + 3) / 4);
  const int CB1 = MPAD * 128 / 1024, CB2 = MPAD * 256 / 1024, CB3 = MPAD * 512 / 1024;

  // ---- layer 1 (fi=128, PW=128, fo=250, NP=256) ----
  prop_kernel<1, 64><<<pgrid, 256, 0, stream>>>(rp, ssrc, sw, x, x, P11, 128, 0);
  prop_kernel<1, 64><<<pgrid, 256, 0, stream>>>(rp, ssrc, sw, P11, x, P12, 128, 1);
  cast_kernel<<<CB1, 256, 0, stream>>>(x, G1_0, 7, 128);
  cast_kernel<<<CB1, 256, 0, stream>>>(P11, G1_1, 7, 128);
  cast_kernel<<<CB1, 256, 0, stream>>>(P12, G1_2, 7, 128);
  gemm_kernel<<<dim3(2, MPAD / 128), 256, 0, stream>>>(G1_0, G1_1, G1_2, WT1h, WT1l,
                                                       7, 256, b1, P20, 256, 250, MPAD);
  // ---- layer 2 (fi=250, PW=256, fo=500, NP=512) ----
  prop_kernel<2, 125><<<pgrid, 256, 0, stream>>>(rp, ssrc, sw, P20, P20, P21, 256, 0);
  prop_kernel<2, 125><<<pgrid, 256, 0, stream>>>(rp, ssrc, sw, P21, P20, P22, 256, 1);
  cast_kernel<<<CB2, 256, 0, stream>>>(P20, G2_0, 8, 250);
  cast_kernel<<<CB2, 256, 0, stream>>>(P21, G2_1, 8, 250);
  cast_kernel<<<CB2, 256, 0, stream>>>(P22, G2_2, 8, 250);
  gemm_kernel<<<dim3(4, MPAD / 128), 256, 0, stream>>>(G2_0, G2_1, G2_2, WT2h, WT2l,
                                                       8, 512, b2, P30, 512, 500, MPAD);
  // ---- layer 3 (fi=500, PW=512, fo=1000, NP=1024) ----
  prop_kernel<4, 250><<<pgrid, 256, 0, stream>>>(rp, ssrc, sw, P30, P30, P31, 512, 0);
  prop_kernel<4, 250><<<pgrid, 256, 0, stream>>>(rp, ssrc, sw, P31, P30, P32, 512, 1);
  cast_kernel<<<CB3, 256, 0, stream>>>(P32, G3_2, 9, 500);   // frees R2
  cast_kernel<<<CB3, 256, 0, stream>>>(P30, G3_0, 9, 500);   // frees R0
  cast_kernel<<<CB3, 256, 0, stream>>>(P31, G3_1, 9, 500);   // frees d_out
  gemm_kernel<<<dim3(8, MPAD / 128), 256, 0, stream>>>(G3_0, G3_1, G3_2, WT3h, WT3l,
                                                       9, 1024, b3, out, 1000, 1000, N_NODES);

  (void)in_sizes; (void)n_in; (void)out_size; (void)ws_size;
}